// Round 6
// baseline (676.829 us; speedup 1.0000x reference)
//
#include <hip/hip_runtime.h>
#include <stdint.h>

// W8A8B32O32 Linear: Y[m,n] = round(out_scale * sum_k X[m,k]*W[n,k] + bias_scale * bias[n])
// Harness materializes integer inputs as int32 -> pre-pass packs to int8 in d_ws (exact),
// then DMA-staged mfma_i32_16x16x64_i8 GEMM.
//
// Round 11: break the barrier-aligned phase lockstep (the shared ~5000-5500 cyc/tile wall
// of R5/R7/R9/R10). Mechanism: reads-then-MFMA between two barriers + fair LDS round-robin
// means ALL waves' reads complete near the end of a ~2300-cyc CU read window, then all
// waves contend the matrix pipe ~2600 cyc -> pipes alternate (serial), never overlap.
// R10's SGB staircase made it worse (ds_read LATENCY ~120+cyc vs 82-cyc 4-MFMA cover;
// per-group stalls + lost compiler slack). SGB staircase removed.
//
// Fix: cross-tile REGISTER double-buffering. Fragments of tile t+1 are ds_read during
// tile t's MFMA stream (no dataflow between them; anti-deps on P/Q keep order):
//   iter t:  A: 32 MFMA k0(t) from P      (covers vmcnt drain of DMA(t+1), issued iter t-1)
//            __syncthreads                 (publishes buf[t+1]; per-wave vmcnt0+lgkm0)
//            C: 12 ds_read k0(t+1) -> P   (complete under D)
//            D: 32 MFMA k1(t) from Q
//            C2: 12 ds_read k1(t+1) -> Q  (complete under next A)
//            E: STAGE(t+2) -> buf[t&1]    (drain covered by A(t+1) before next sync)
// Per window: MFMA 2612 cyc/SIMD overlaps LDS 2304(read)+512(DMA write) cyc -> ~2900-3400
// cyc/tile vs 5475 measured in R9.
//
// Hazard ledger (1 barrier/tile):
//   C/C2 read buf[(t+1)&1]: published at B(t) (E(t-1) drained by every wave's vmcnt(0)
//     at B(t), collective via barrier)  -> safe
//   E(t) overwrites buf[t&1] (tile t): tile t's only LDS reads were C(t-1)/C2(t-1),
//     retired by B(t)'s lgkmcnt(0)+barrier; E(t) is after B(t)  -> safe
//   P/Q anti-dependencies: C writes P after A reads P; C2 writes Q after D reads Q.
//   Tail: C/C2/E guarded (t+1/t+2 < KT), guards wave-uniform, no barriers inside.
//   Prologue = "iter -1": stage(0); sync; read tile0 -> P,Q; stage(1).
//
// Registers: acc 128 + P(a0[8],b0[4]) 48 + Q(a1[8],b1[4]) 48 = 224 + addr/misc ~ 240.
// If VGPR hits 256 w/ scratch traffic (FETCH/WRITE inflated) -> pressure, cut next round.
//
// NOTE: per-replay dur_us includes ~240us fixed harness restore/poison; GEMM is the lever.

typedef int v4i __attribute__((ext_vector_type(4)));

#define BM 256
#define BN 256
#define BK 128
#define KK 4096
#define KT (KK / BK)   // 32

// ---------------- pack: 4x int32 -> 4x int8 in one dword (coalesced, ~roofline) ----------------
__global__ __launch_bounds__(256)
void pack_i32_to_i8(const v4i* __restrict__ src, int* __restrict__ dst, int n4) {
    int i = blockIdx.x * blockDim.x + threadIdx.x;   // one thread = 4 elements
    if (i >= n4) return;
    v4i a = src[i];
    dst[i] = (a[0] & 0xff) | ((a[1] & 0xff) << 8) | ((a[2] & 0xff) << 16) | (a[3] << 24);
}

// ---------------- GEMM ----------------
__device__ __forceinline__ void gld_lds16(const void* g, void* lds) {
    __builtin_amdgcn_global_load_lds(
        (const __attribute__((address_space(1))) unsigned int*)g,
        (__attribute__((address_space(3))) unsigned int*)lds,
        16, 0, 0);
}

#define MFMA_I8 __builtin_amdgcn_mfma_i32_16x16x64_i8
#define SB0()   __builtin_amdgcn_sched_barrier(0)

__global__ __launch_bounds__(512, 2)
void w8a8_gemm_kernel(const int8_t* __restrict__ X,
                      const int8_t* __restrict__ W,
                      const int*    __restrict__ bias,
                      const float*  __restrict__ out_scale_p,
                      const float*  __restrict__ bias_scale_p,
                      int*          __restrict__ Y,
                      int M, int N)
{
    __shared__ __align__(16) int8_t sA[2 * BM * BK];  // 64 KB (double-buffered)
    __shared__ __align__(16) int8_t sB[2 * BN * BK];  // 64 KB

    const int tid = threadIdx.x;         // 0..511

    // ---- block -> tile mapping with 2D XCD chunking (8 XCDs, each owns 8x8 tiles) ----
    const int nbx = N / BN;              // 16 expected
    const int nby = M / BM;              // 32 expected
    int bx, by;
    {
        const int wg = blockIdx.x;
        if (nbx == 16 && nby == 32) {
            const int x = wg & 7;        // XCD (dispatch round-robins blockIdx % 8)
            const int k = wg >> 3;       // 0..63 within XCD
            bx = ((x & 1) << 3) | (k & 7);
            by = ((x >> 1) << 3) | (k >> 3);
        } else { bx = wg % nbx; by = wg / nbx; }
    }
    const int bn = bx * BN;
    const int bm = by * BM;

    const float out_scale  = *out_scale_p;
    const float bias_scale = *bias_scale_p;

    const int8_t* Abase = X + (size_t)bm * KK;
    const int8_t* Bbase = W + (size_t)bn * KK;

    // ---- staging thread map: half-tile = 128 rows x 8 chunks(16B), 2 gld rounds ----
    // LDS slot c (linear) holds global chunk (c&7)^(row&7) of row c>>3 -> XOR swizzle
    // via SOURCE address permutation; LDS dest stays linear (DMA-compatible).
    const int r0  = tid >> 3;                       // 0..63 (round 0 rows; round 1 = +64)
    const int j0  = tid & 7;
    const int sw  = (j0 ^ (r0 & 7)) << 4;           // pre-swizzled in-row byte offset
    const size_t gOff = (size_t)r0 * KK + sw;
    const int  lOff = tid << 4;

#define STAGE(gbase, lds, t, h) do {                                              \
        const int8_t* _g = (gbase) + (size_t)((h) * 128) * KK                     \
                                   + (size_t)(t) * BK + gOff;                     \
        int8_t* _l = (lds) + (((t) & 1) << 15) + ((h) << 14) + lOff;              \
        gld_lds16(_g,                  _l);                                       \
        gld_lds16(_g + (size_t)64 * KK, _l + 8192);                               \
    } while (0)

    // ---- fragment read map (verified 16x16x64 layout: lane = (tm, quad)) ----
    const int w    = tid >> 6;
    const int l    = tid & 63;
    const int wmw  = w >> 2;                        // 0..1  (M wave)
    const int wnw  = w & 3;                         // 0..3  (N wave)
    const int tm   = l & 15;
    const int quad = l >> 4;
    const int s3   = tm & 7;                        // row&7 (wave row bases are mult of 8)
    const int xo0  = ( quad      ^ s3) << 4;        // kslice 0: chunk quad
    const int xo1  = ((quad + 4) ^ s3) << 4;        // kslice 1: chunk 4+quad
    const int rowA = ((wmw << 7) + tm) << 7;        // (wm*128+tm)*128 bytes
    const int rowB = ((wnw << 6) + tm) << 7;        // (wn*64 +tm)*128 bytes

    v4i acc[8][4];
    const v4i vz = {0, 0, 0, 0};
#pragma unroll
    for (int i = 0; i < 8; ++i)
#pragma unroll
        for (int j = 0; j < 4; ++j)
            acc[i][j] = vz;

    // ---- persistent register fragments (cross-tile double-buffer) ----
    v4i a0[8], b0[4];   // P: k-slice 0 of current tile
    v4i a1[8], b1[4];   // Q: k-slice 1 of current tile

    // ---- prologue ("iter -1"): stage tile0, land it, read its frags, stage tile1 ----
    STAGE(Abase, sA, 0, 0); STAGE(Abase, sA, 0, 1);
    STAGE(Bbase, sB, 0, 0); STAGE(Bbase, sB, 0, 1);
    __syncthreads();   // vmcnt(0): tile 0 landed
#pragma unroll
    for (int i = 0; i < 8; ++i) {
        a0[i] = *(const v4i*)(sA + rowA + i * 2048 + xo0);
        a1[i] = *(const v4i*)(sA + rowA + i * 2048 + xo1);
    }
#pragma unroll
    for (int j = 0; j < 4; ++j) {
        b0[j] = *(const v4i*)(sB + rowB + j * 2048 + xo0);
        b1[j] = *(const v4i*)(sB + rowB + j * 2048 + xo1);
    }
    STAGE(Abase, sA, 1, 0); STAGE(Abase, sA, 1, 1);   // E(-1): tile1 -> buf1
    STAGE(Bbase, sB, 1, 0); STAGE(Bbase, sB, 1, 1);
    SB0();

#pragma unroll 2
    for (int t = 0; t < KT; ++t) {
        const int bo1 = ((t + 1) & 1) << 15;          // buffer holding tile t+1
        const int8_t* sA1 = sA + bo1;
        const int8_t* sB1 = sB + bo1;

        // ---- A: MFMA k-slice 0 of tile t (frees P); covers drain of DMA(t+1) ----
#pragma unroll
        for (int i = 0; i < 8; ++i)
#pragma unroll
            for (int j = 0; j < 4; ++j)
                acc[i][j] = MFMA_I8(a0[i], b0[j], acc[i][j], 0, 0, 0);
        SB0();
        __syncthreads();   // publishes buf[t+1] (DMA issued iter t-1, ~2600 cyc old => free)

        // ---- C: read k-slice 0 of tile t+1 -> P (completes under D) ----
        if (t + 1 < KT) {
#pragma unroll
            for (int i = 0; i < 8; ++i)
                a0[i] = *(const v4i*)(sA1 + rowA + i * 2048 + xo0);
#pragma unroll
            for (int j = 0; j < 4; ++j)
                b0[j] = *(const v4i*)(sB1 + rowB + j * 2048 + xo0);
        }
        SB0();

        // ---- D: MFMA k-slice 1 of tile t (frees Q) ----
#pragma unroll
        for (int i = 0; i < 8; ++i)
#pragma unroll
            for (int j = 0; j < 4; ++j)
                acc[i][j] = MFMA_I8(a1[i], b1[j], acc[i][j], 0, 0, 0);

        // ---- C2: read k-slice 1 of tile t+1 -> Q (anti-dep keeps after D;
        //          completes under next iteration's A) ----
        if (t + 1 < KT) {
#pragma unroll
            for (int i = 0; i < 8; ++i)
                a1[i] = *(const v4i*)(sA1 + rowA + i * 2048 + xo1);
#pragma unroll
            for (int j = 0; j < 4; ++j)
                b1[j] = *(const v4i*)(sB1 + rowB + j * 2048 + xo1);
        }

        // ---- E: stage tile t+2 into buf[t&1] (drain covered by next A) ----
        if (t + 2 < KT) {
            STAGE(Abase, sA, t + 2, 0); STAGE(Abase, sA, t + 2, 1);
            STAGE(Bbase, sB, t + 2, 0); STAGE(Bbase, sB, t + 2, 1);
        }
        SB0();
    }
#undef STAGE

    // ---- epilogue. C/D layout (verified): col(n)=lane&15, row(m)=quad*4+reg ----
    // j-inner store order: both 64B halves of each 128B L2 line written back-to-back.
    float bb[4];
#pragma unroll
    for (int j = 0; j < 4; ++j)
        bb[j] = (float)bias[bn + (wnw << 6) + (j << 4) + tm] * bias_scale;
#pragma unroll
    for (int i = 0; i < 8; ++i) {
        const int mb = bm + (wmw << 7) + (i << 4) + (quad << 2);
#pragma unroll
        for (int r = 0; r < 4; ++r) {
            int* yrow = Y + (size_t)(mb + r) * N + bn + (wnw << 6) + tm;
#pragma unroll
            for (int j = 0; j < 4; ++j) {
                const float v = (float)acc[i][j][r] * out_scale + bb[j];
                yrow[j << 4] = (int)rintf(v);
            }
        }
    }
}

extern "C" void kernel_launch(void* const* d_in, const int* in_sizes, int n_in,
                              void* d_out, int out_size, void* d_ws, size_t ws_size,
                              hipStream_t stream) {
    const int* x32 = (const int*)d_in[0];   // int8 values stored as int32
    const int* w32 = (const int*)d_in[1];
    const int*    bias = (const int*)d_in[2];
    const float*  os   = (const float*)d_in[3];
    const float*  bs   = (const float*)d_in[4];
    int* out = (int*)d_out;

    const int K = KK;
    const int M = in_sizes[0] / K;   // 8192
    const int N = in_sizes[1] / K;   // 4096
    const int nx = in_sizes[0];      // 33554432
    const int nw = in_sizes[1];      // 16777216

    int8_t* x8 = (int8_t*)d_ws;              // 33.5 MB
    int8_t* w8 = x8 + (size_t)nx;            // 16.8 MB  (total 50.3 MB < ws_size)

    pack_i32_to_i8<<<dim3(nx / 4 / 256), dim3(256), 0, stream>>>((const v4i*)x32, (int*)x8, nx / 4);
    pack_i32_to_i8<<<dim3(nw / 4 / 256), dim3(256), 0, stream>>>((const v4i*)w32, (int*)w8, nw / 4);

    dim3 grid((N / BN) * (M / BM));  // (32, 64) tiles -> 512 blocks = 2 rounds of 256 CUs
    dim3 block(512);
    hipLaunchKernelGGL(w8a8_gemm_kernel, grid, block, 0, stream,
                       x8, w8, bias, os, bs, out, M, N);
}

// Round 7
// 393.608 us; speedup vs baseline: 1.7196x; 1.7196x over previous
//
#include <hip/hip_runtime.h>
#include <stdint.h>

// W8A8B32O32 Linear: Y[m,n] = round(out_scale * sum_k X[m,k]*W[n,k] + bias_scale * bias[n])
// Harness materializes integer inputs as int32 -> pre-pass packs to int8 in d_ws (exact),
// then DMA-staged mfma_i32_16x16x64_i8 GEMM.
//
// Round 12: the clean single-variable experiment R10 should have been.
// R9 theory (unrefuted): reads issued a[0..7],b[0..3] but first MFMA consumes b[0..3]
// = reads #9-12; DS ops retire in order -> compiler waits all 12 reads before any MFMA,
// serializing a ~1150-cyc CU-wide read burst against the 1306-cyc MFMA stream, twice per
// tile (model 5300 ~= measured 5475 cyc/tile). R10 tested the fix confounded with an SGB
// staircase whose {1R,4M} groups stall on ds_read LATENCY (~120cyc vs 82-cyc cover) ->
// regression came from the staircase, not the order. R11's register double-buffer spilled
// (VGPR capped 128, WRITE_SIZE 725MB scratch traffic) -> dead end.
// This round: R9 EXACTLY, with reads in CONSUMPTION order b0,a0,b1,b2,b3,a1..a7 and the
// compiler left free (no sched_group_barrier). First 4-MFMA group waits only 5 reads
// (counted lgkmcnt); remaining 7 reads hide under the MFMA stream.
//
//  - 256x256 tile, BK=128, 8 waves (2M x 4N -> 128x64/wave), double-buffered 128 KiB LDS
//  - XOR chunk swizzle (chunk j of row r at slot j^(r&7)) via pre-swizzled global source
//    addresses; LDS dest linear (DMA-compatible); zero bank conflicts (verified R6-R11)
//  - per K-tile t: STAGE(t+1 -> buf^1) ; sched_barrier ; {slice0, slice1} ; __syncthreads()
//
// Hazard ledger (1 barrier/tile) -- unchanged from R9:
//   entry of iter t: buf[t&1] fully landed (all waves drained vmcnt(0) at bottom of t-1)
//   STAGE t+1 -> buf[(t+1)&1] overwrites tile t-1: reads of t-1 drained at bottom-of-(t-1)
//     lgkmcnt(0)+barrier -> safe; reads buf[t&1] vs DMA into buf^1: disjoint -> safe
//   __syncthreads drains own staging (issued ~3000 cyc earlier, HBM lat ~900) => free
//
// NOTE: per-replay dur_us includes ~240us fixed harness restore/poison; GEMM is the lever.

typedef int v4i __attribute__((ext_vector_type(4)));

#define BM 256
#define BN 256
#define BK 128
#define KK 4096
#define KT (KK / BK)   // 32

// ---------------- pack: 4x int32 -> 4x int8 in one dword (coalesced, ~roofline) ----------------
__global__ __launch_bounds__(256)
void pack_i32_to_i8(const v4i* __restrict__ src, int* __restrict__ dst, int n4) {
    int i = blockIdx.x * blockDim.x + threadIdx.x;   // one thread = 4 elements
    if (i >= n4) return;
    v4i a = src[i];
    dst[i] = (a[0] & 0xff) | ((a[1] & 0xff) << 8) | ((a[2] & 0xff) << 16) | (a[3] << 24);
}

// ---------------- GEMM ----------------
__device__ __forceinline__ void gld_lds16(const void* g, void* lds) {
    __builtin_amdgcn_global_load_lds(
        (const __attribute__((address_space(1))) unsigned int*)g,
        (__attribute__((address_space(3))) unsigned int*)lds,
        16, 0, 0);
}

#define MFMA_I8 __builtin_amdgcn_mfma_i32_16x16x64_i8

// Consumption-ordered slice, compiler-scheduled (NO sched_group_barrier).
// Reads: b0,a0,b1,b2,b3 (first MFMA group's operands), then a1..a7.
// MFMA i-outer j-inner: group i consumes a[i] (read #5+i) -> counted lgkmcnt lets
// group 0 start after 5 reads; reads a1..a7 complete under groups 0..6.
#define COMPUTE_SLICE(XO) do {                                                    \
    v4i a[8], b[4];                                                               \
    b[0] = *(const v4i*)(sBb + rowB + 0 * 2048 + (XO));                           \
    a[0] = *(const v4i*)(sAb + rowA + 0 * 2048 + (XO));                           \
    b[1] = *(const v4i*)(sBb + rowB + 1 * 2048 + (XO));                           \
    b[2] = *(const v4i*)(sBb + rowB + 2 * 2048 + (XO));                           \
    b[3] = *(const v4i*)(sBb + rowB + 3 * 2048 + (XO));                           \
    _Pragma("unroll")                                                             \
    for (int i = 1; i < 8; ++i)                                                   \
        a[i] = *(const v4i*)(sAb + rowA + i * 2048 + (XO));                       \
    _Pragma("unroll")                                                             \
    for (int i = 0; i < 8; ++i)                                                   \
        _Pragma("unroll")                                                         \
        for (int j = 0; j < 4; ++j)                                               \
            acc[i][j] = MFMA_I8(a[i], b[j], acc[i][j], 0, 0, 0);                  \
} while (0)

__global__ __launch_bounds__(512, 2)
void w8a8_gemm_kernel(const int8_t* __restrict__ X,
                      const int8_t* __restrict__ W,
                      const int*    __restrict__ bias,
                      const float*  __restrict__ out_scale_p,
                      const float*  __restrict__ bias_scale_p,
                      int*          __restrict__ Y,
                      int M, int N)
{
    __shared__ __align__(16) int8_t sA[2 * BM * BK];  // 64 KB (double-buffered)
    __shared__ __align__(16) int8_t sB[2 * BN * BK];  // 64 KB

    const int tid = threadIdx.x;         // 0..511

    // ---- block -> tile mapping with 2D XCD chunking (8 XCDs, each owns 8x8 tiles) ----
    const int nbx = N / BN;              // 16 expected
    const int nby = M / BM;              // 32 expected
    int bx, by;
    {
        const int wg = blockIdx.x;
        if (nbx == 16 && nby == 32) {
            const int x = wg & 7;        // XCD (dispatch round-robins blockIdx % 8)
            const int k = wg >> 3;       // 0..63 within XCD
            bx = ((x & 1) << 3) | (k & 7);
            by = ((x >> 1) << 3) | (k >> 3);
        } else { bx = wg % nbx; by = wg / nbx; }
    }
    const int bn = bx * BN;
    const int bm = by * BM;

    const float out_scale  = *out_scale_p;
    const float bias_scale = *bias_scale_p;

    const int8_t* Abase = X + (size_t)bm * KK;
    const int8_t* Bbase = W + (size_t)bn * KK;

    // ---- staging thread map: half-tile = 128 rows x 8 chunks(16B), 2 gld rounds ----
    // LDS slot c (linear) holds global chunk (c&7)^(row&7) of row c>>3 -> XOR swizzle
    // via SOURCE address permutation; LDS dest stays linear (DMA-compatible).
    const int r0  = tid >> 3;                       // 0..63 (round 0 rows; round 1 = +64)
    const int j0  = tid & 7;
    const int sw  = (j0 ^ (r0 & 7)) << 4;           // pre-swizzled in-row byte offset
    const size_t gOff = (size_t)r0 * KK + sw;
    const int  lOff = tid << 4;

#define STAGE(gbase, lds, t, h) do {                                              \
        const int8_t* _g = (gbase) + (size_t)((h) * 128) * KK                     \
                                   + (size_t)(t) * BK + gOff;                     \
        int8_t* _l = (lds) + (((t) & 1) << 15) + ((h) << 14) + lOff;              \
        gld_lds16(_g,                  _l);                                       \
        gld_lds16(_g + (size_t)64 * KK, _l + 8192);                               \
    } while (0)

    // ---- fragment read map (verified 16x16x64 layout: lane = (tm, quad)) ----
    const int w    = tid >> 6;
    const int l    = tid & 63;
    const int wmw  = w >> 2;                        // 0..1  (M wave)
    const int wnw  = w & 3;                         // 0..3  (N wave)
    const int tm   = l & 15;
    const int quad = l >> 4;
    const int s3   = tm & 7;                        // row&7 (wave row bases are mult of 8)
    const int xo0  = ( quad      ^ s3) << 4;        // kslice 0: chunk quad
    const int xo1  = ((quad + 4) ^ s3) << 4;        // kslice 1: chunk 4+quad
    const int rowA = ((wmw << 7) + tm) << 7;        // (wm*128+tm)*128 bytes
    const int rowB = ((wnw << 6) + tm) << 7;        // (wn*64 +tm)*128 bytes

    v4i acc[8][4];
    const v4i vz = {0, 0, 0, 0};
#pragma unroll
    for (int i = 0; i < 8; ++i)
#pragma unroll
        for (int j = 0; j < 4; ++j)
            acc[i][j] = vz;

    // ---- prologue: stage tile 0 into buf0, land it ----
    STAGE(Abase, sA, 0, 0); STAGE(Abase, sA, 0, 1);
    STAGE(Bbase, sB, 0, 0); STAGE(Bbase, sB, 0, 1);
    __syncthreads();   // vmcnt(0): tile 0 landed

#pragma unroll 2
    for (int t = 0; t < KT; ++t) {
        const int bo = (t & 1) << 15;
        const int8_t* sAb = sA + bo;
        const int8_t* sBb = sB + bo;

        // ---- stage tile t+1 into the other buffer (max slack before the drain) ----
        if (t + 1 < KT) {
            STAGE(Abase, sA, t + 1, 0); STAGE(Abase, sA, t + 1, 1);
            STAGE(Bbase, sB, t + 1, 0); STAGE(Bbase, sB, t + 1, 1);
        }
        __builtin_amdgcn_sched_barrier(0);   // region split: staging stays at top

        // ---- compute tile t: consumption-ordered reads, compiler-scheduled ----
        COMPUTE_SLICE(xo0);
        COMPUTE_SLICE(xo1);

        // ---- single barrier: drains own staging loads (issued ~3000 cyc ago => free)
        //      + own ds_reads; publishes buf[t+1], retires buf[t] reads for all waves ----
        __syncthreads();
    }
#undef STAGE

    // ---- epilogue. C/D layout (verified): col(n)=lane&15, row(m)=quad*4+reg ----
    // j-inner store order: both 64B halves of each 128B L2 line written back-to-back.
    float bb[4];
#pragma unroll
    for (int j = 0; j < 4; ++j)
        bb[j] = (float)bias[bn + (wnw << 6) + (j << 4) + tm] * bias_scale;
#pragma unroll
    for (int i = 0; i < 8; ++i) {
        const int mb = bm + (wmw << 7) + (i << 4) + (quad << 2);
#pragma unroll
        for (int r = 0; r < 4; ++r) {
            int* yrow = Y + (size_t)(mb + r) * N + bn + (wnw << 6) + tm;
#pragma unroll
            for (int j = 0; j < 4; ++j) {
                const float v = (float)acc[i][j][r] * out_scale + bb[j];
                yrow[j << 4] = (int)rintf(v);
            }
        }
    }
}

extern "C" void kernel_launch(void* const* d_in, const int* in_sizes, int n_in,
                              void* d_out, int out_size, void* d_ws, size_t ws_size,
                              hipStream_t stream) {
    const int* x32 = (const int*)d_in[0];   // int8 values stored as int32
    const int* w32 = (const int*)d_in[1];
    const int*    bias = (const int*)d_in[2];
    const float*  os   = (const float*)d_in[3];
    const float*  bs   = (const float*)d_in[4];
    int* out = (int*)d_out;

    const int K = KK;
    const int M = in_sizes[0] / K;   // 8192
    const int N = in_sizes[1] / K;   // 4096
    const int nx = in_sizes[0];      // 33554432
    const int nw = in_sizes[1];      // 16777216

    int8_t* x8 = (int8_t*)d_ws;              // 33.5 MB
    int8_t* w8 = x8 + (size_t)nx;            // 16.8 MB  (total 50.3 MB < ws_size)

    pack_i32_to_i8<<<dim3(nx / 4 / 256), dim3(256), 0, stream>>>((const v4i*)x32, (int*)x8, nx / 4);
    pack_i32_to_i8<<<dim3(nw / 4 / 256), dim3(256), 0, stream>>>((const v4i*)w32, (int*)w8, nw / 4);

    dim3 grid((N / BN) * (M / BM));  // (32, 64) tiles -> 512 blocks = 2 rounds of 256 CUs
    dim3 block(512);
    hipLaunchKernelGGL(w8a8_gemm_kernel, grid, block, 0, stream,
                       x8, w8, bias, os, bs, out, M, N);
}